// Round 9
// baseline (469.950 us; speedup 1.0000x reference)
//
#include <hip/hip_runtime.h>
#include <hip/hip_fp16.h>

// GCN forward: 3x (GCNConv improved + ReLU) + GCNConv(out, 1 feature)
// N=50000, E=1.6M, H=64. CSR via atomic-free MSD counting sort.
// R7 profile: agg misses = 8 XCD x table (compulsory per-XCD L2 fills) at
// ~1 TB/s random-demand service rate. This round: feature-split tables
// (2x 3.2MB slices, each fits 4MB XCD L2) + streaming L2 prime prologue
// (blockIdx&7 XCD heuristic) + nontemporal agg stores (scalar form —
// __builtin_nontemporal_store rejects HIP_vector_type).

#define HF 64
#define EPB 4096          // edges per block in passes A/B
#define AGG_GRID 2048     // fixed agg grid: 8 blocks/CU, all co-resident

// ---------------- pass A: coarse histogram (bucket = dst>>8) ----------------
__global__ __launch_bounds__(256) void pA_hist(const int* __restrict__ dst,
                                               int* __restrict__ histT, int E, int G) {
    __shared__ int h[256];
    int g = blockIdx.x, t = threadIdx.x;
    h[t] = 0;
    __syncthreads();
    int beg = g * EPB, end = min(beg + EPB, E);
    for (int i = beg + t; i < end; i += 256) atomicAdd(&h[dst[i] >> 8], 1);
    __syncthreads();
    histT[t * G + g] = h[t];
}

// ---------------- scan: linear exclusive scan of histT (bucket-major) --------
#define ST 1024
__global__ __launch_bounds__(ST) void pScan(int* __restrict__ hist,
                                            int* __restrict__ coarse, int G, int E) {
    __shared__ int sd[ST];
    int t = threadIdx.x;
    int M = 256 * G;
    int chunk = (M + ST - 1) / ST;
    int beg = t * chunk, end = min(beg + chunk, M);
    int s = 0;
    for (int fi = beg; fi < end; ++fi) s += hist[fi];
    sd[t] = s;
    __syncthreads();
    for (int o = 1; o < ST; o <<= 1) {
        int u = (t >= o) ? sd[t - o] : 0;
        __syncthreads();
        sd[t] += u;
        __syncthreads();
    }
    int run = sd[t] - s;
    for (int fi = beg; fi < end; ++fi) {
        int v = hist[fi];
        hist[fi] = run;
        if (fi % G == 0) coarse[fi / G] = run;
        run += v;
    }
    if (t == ST - 1) coarse[256] = E;
}

// ---------------- pass B: coarse scatter (LDS cursors) ----------------
__global__ __launch_bounds__(256) void pB_scatter(const int* __restrict__ src,
                                                  const int* __restrict__ dst,
                                                  const int* __restrict__ histT,
                                                  unsigned int* __restrict__ tmp,
                                                  int E, int G) {
    __shared__ int cur[256];
    int g = blockIdx.x, t = threadIdx.x;
    cur[t] = histT[t * G + g];
    __syncthreads();
    int beg = g * EPB, end = min(beg + EPB, E);
    for (int i = beg + t; i < end; i += 256) {
        int d = dst[i], s = src[i];
        int pos = atomicAdd(&cur[d >> 8], 1);
        tmp[pos] = ((unsigned int)(d & 255) << 16) | (unsigned int)(s & 0xFFFF);
    }
}

// ---------------- pass C: per-bucket fine counting sort + CSR metadata -------
__global__ __launch_bounds__(256) void pC_build(const unsigned int* __restrict__ tmp,
                                                const int* __restrict__ coarse,
                                                ushort* __restrict__ csrs,
                                                int* __restrict__ offs,
                                                float* __restrict__ di,
                                                float* __restrict__ dp,
                                                int n, int E, int NB) {
    __shared__ int hist[256];
    __shared__ int cur[256];
    __shared__ int scanbuf[256];
    int b = blockIdx.x, t = threadIdx.x;
    int beg = coarse[b], end = coarse[b + 1];
    hist[t] = 0;
    __syncthreads();
    for (int i = beg + t; i < end; i += 256) atomicAdd(&hist[tmp[i] >> 16], 1);
    __syncthreads();
    int v = hist[t];
    scanbuf[t] = v;
    __syncthreads();
    for (int o = 1; o < 256; o <<= 1) {
        int u = (t >= o) ? scanbuf[t - o] : 0;
        __syncthreads();
        scanbuf[t] += u;
        __syncthreads();
    }
    int excl = scanbuf[t] - v;
    cur[t] = beg + excl;
    int d = (b << 8) + t;
    if (d < n) {
        offs[d] = beg + excl;
        float df = (float)v;
        di[d] = rsqrtf(df + 2.0f);   // improved=True: self-loop weight 2
        dp[d] = rsqrtf(df + 1.0f);   // output layer: improved=False
    }
    if (b == NB - 1 && t == 0) offs[n] = E;
    __syncthreads();
    for (int i = beg + t; i < end; i += 256) {
        unsigned int e = tmp[i];
        int pos = atomicAdd(&cur[e >> 16], 1);
        csrs[pos] = (ushort)(e & 0xFFFFu);
    }
}

// ---- dense GEMM: [C0|C1][n,32] = di[n] * (A[n,64] @ W[64,64]) in fp16 -------
#define GM_BN 128
__global__ __launch_bounds__(256) void k_gemm(const float* __restrict__ A,
                                              const float* __restrict__ W,
                                              const float* __restrict__ di,
                                              __half* __restrict__ C0,
                                              __half* __restrict__ C1, int n) {
    __shared__ float xT[64][132];
    __shared__ float Wl[64][64];
    int tid = threadIdx.x;
    int nb = blockIdx.x * GM_BN;

    for (int r = 0; r < 4; ++r) {
        int q = tid + 256 * r;
        int row = q >> 4, c4 = (q & 15) << 2;
        *(float4*)&Wl[row][c4] = *(const float4*)&W[row * 64 + c4];
    }
    for (int r = 0; r < 8; ++r) {
        int q = tid + 256 * r;
        int nl = q >> 4, k0 = (q & 15) << 2;
        float4 v = make_float4(0.f, 0.f, 0.f, 0.f);
        if (nb + nl < n) v = *(const float4*)&A[(size_t)(nb + nl) * HF + k0];
        xT[k0 + 0][nl] = v.x; xT[k0 + 1][nl] = v.y;
        xT[k0 + 2][nl] = v.z; xT[k0 + 3][nl] = v.w;
    }
    __syncthreads();

    int tx = tid & 7;
    int ty = tid >> 3;
    int f0 = tx * 8, n0 = ty * 4;
    float acc[4][8];
#pragma unroll
    for (int i = 0; i < 4; ++i)
#pragma unroll
        for (int j = 0; j < 8; ++j) acc[i][j] = 0.f;

#pragma unroll 4
    for (int k = 0; k < 64; ++k) {
        float4 xa = *(float4*)&xT[k][n0];
        float4 wa = *(float4*)&Wl[k][f0];
        float4 wb = *(float4*)&Wl[k][f0 + 4];
        float xs[4] = {xa.x, xa.y, xa.z, xa.w};
        float wsv[8] = {wa.x, wa.y, wa.z, wa.w, wb.x, wb.y, wb.z, wb.w};
#pragma unroll
        for (int i = 0; i < 4; ++i)
#pragma unroll
            for (int j = 0; j < 8; ++j) acc[i][j] += xs[i] * wsv[j];
    }

    __half* Ct = (f0 < 32) ? C0 : C1;
    int cc = f0 & 31;
#pragma unroll
    for (int i = 0; i < 4; ++i) {
        int nn = nb + n0 + i;
        if (nn < n) {
            float dr = di[nn];                  // fold edge weight into table
            union { __half h[8]; float4 f4; } u;
#pragma unroll
            for (int j = 0; j < 8; ++j) u.h[j] = __float2half(acc[i][j] * dr);
            *(float4*)&Ct[(size_t)nn * 32 + cc] = u.f4;
        }
    }
}

// ---------------- L2 prime: stream this XCD's copy of the 3.2MB slice --------
__device__ __forceinline__ void prime_slice(const __half2* __restrict__ P2, int n) {
    const float4* sp = (const float4*)P2;
    int nf4 = n * 4;                       // 64B/row = 4 float4
    int j = blockIdx.x >> 3;               // rank within presumed-XCD class
    int nc = AGG_GRID >> 3;
    int per = (nf4 + nc - 1) / nc;
    int pb = j * per, pe = min(pb + per, nf4);
    float dummy = 0.f;
    for (int i = pb + threadIdx.x; i < pe; i += 256) {
        float4 v = sp[i];
        dummy += v.x + v.y + v.z + v.w;
    }
    asm volatile("" :: "v"(dummy));        // keep loads alive
}

// ---------------- agg pass: 32 features, 4 edge-slots per wave ---------------
// lane = (slot = lane>>4, fh = lane&15); P2 row = 16 half2 (64B, one line)
__global__ __launch_bounds__(256) void k_agg(const __half2* __restrict__ P2,
        const int* __restrict__ offs, const ushort* __restrict__ csrs,
        const float* __restrict__ di, const float* __restrict__ bias, int fbase,
        float* __restrict__ out, int n, float fill) {
    prime_slice(P2, n);
    int lane = threadIdx.x & 63;
    int slot = lane >> 4, fh = lane & 15;
    int wid0 = (blockIdx.x * 256 + threadIdx.x) >> 6;
    int nw = gridDim.x << 2;
    for (int node = wid0; node < n; node += nw) {
        int beg = offs[node], end = offs[node + 1];
        float a0 = 0.f, a1 = 0.f;
        for (int e = beg + slot; e < end; e += 4) {
            int s = csrs[e];
            float2 v = __half22float2(P2[(size_t)s * 16 + fh]);
            a0 += v.x; a1 += v.y;
        }
        a0 += __shfl_xor(a0, 16); a0 += __shfl_xor(a0, 32);
        a1 += __shfl_xor(a1, 16); a1 += __shfl_xor(a1, 32);
        float dw = di[node];
        float2 self = __half22float2(P2[(size_t)node * 16 + fh]);
        float r0 = fmaxf(dw * (a0 + fill * self.x) + bias[fbase + 2 * fh + 0], 0.f);
        float r1 = fmaxf(dw * (a1 + fill * self.y) + bias[fbase + 2 * fh + 1], 0.f);
        if (slot == 0) {
            float* op = &out[(size_t)node * HF + fbase + 2 * fh];
            __builtin_nontemporal_store(r0, op);
            __builtin_nontemporal_store(r1, op + 1);
        }
    }
}

// layer-3 agg pass fused with output projection: z2 (+)= dp * partial-dot
__global__ __launch_bounds__(256) void k_agg_final(const __half2* __restrict__ P2,
        const int* __restrict__ offs, const ushort* __restrict__ csrs,
        const float* __restrict__ di, const float* __restrict__ bias, int fbase,
        const float* __restrict__ Wout, const float* __restrict__ dp,
        float* __restrict__ z2, int n, int accum) {
    prime_slice(P2, n);
    int lane = threadIdx.x & 63;
    int slot = lane >> 4, fh = lane & 15;
    int wid0 = (blockIdx.x * 256 + threadIdx.x) >> 6;
    int nw = gridDim.x << 2;
    for (int node = wid0; node < n; node += nw) {
        int beg = offs[node], end = offs[node + 1];
        float a0 = 0.f, a1 = 0.f;
        for (int e = beg + slot; e < end; e += 4) {
            int s = csrs[e];
            float2 v = __half22float2(P2[(size_t)s * 16 + fh]);
            a0 += v.x; a1 += v.y;
        }
        a0 += __shfl_xor(a0, 16); a0 += __shfl_xor(a0, 32);
        a1 += __shfl_xor(a1, 16); a1 += __shfl_xor(a1, 32);
        float dw = di[node];
        float2 self = __half22float2(P2[(size_t)node * 16 + fh]);
        float r0 = fmaxf(dw * (a0 + 2.0f * self.x) + bias[fbase + 2 * fh + 0], 0.f);
        float r1 = fmaxf(dw * (a1 + 2.0f * self.y) + bias[fbase + 2 * fh + 1], 0.f);
        float v = r0 * Wout[fbase + 2 * fh] + r1 * Wout[fbase + 2 * fh + 1];
#pragma unroll
        for (int o = 8; o > 0; o >>= 1) v += __shfl_down(v, o, 16);
        if (lane == 0) {
            float val = v * dp[node];
            if (accum) z2[node] += val; else z2[node] = val;
        }
    }
}

// out[n] = dp[n] * (sum_e z2[src] + z2[n]) + b_out
__global__ void k_out(const float* __restrict__ z2, const int* __restrict__ offs,
                      const ushort* __restrict__ csrs, const float* __restrict__ dp,
                      const float* __restrict__ bout, float* __restrict__ out, int n) {
    int i = blockIdx.x * blockDim.x + threadIdx.x;
    if (i >= n) return;
    int beg = offs[i], end = offs[i + 1];
    float acc = 0.f;
    for (int e = beg; e < end; ++e) acc += z2[csrs[e]];
    out[i] = dp[i] * (acc + z2[i]) + bout[0];
}

extern "C" void kernel_launch(void* const* d_in, const int* in_sizes, int n_in,
                              void* d_out, int out_size, void* d_ws, size_t ws_size,
                              hipStream_t stream) {
    const float* x    = (const float*)d_in[0];
    const int*   ei   = (const int*)d_in[1];
    const float* W_in = (const float*)d_in[2];
    const float* b_in = (const float*)d_in[3];
    const float* W_h1 = (const float*)d_in[4];
    const float* b_h1 = (const float*)d_in[5];
    const float* W_h2 = (const float*)d_in[6];
    const float* b_h2 = (const float*)d_in[7];
    const float* W_out= (const float*)d_in[8];
    const float* b_out= (const float*)d_in[9];
    float* out = (float*)d_out;

    const int n = in_sizes[0] / HF;        // 50000 (< 65536: ushort CSR ok)
    const int E = in_sizes[1] / 2;         // 1.6M
    const int* src = ei;
    const int* dst = ei + E;

    const int G  = (E + EPB - 1) / EPB;
    const int NB = (n + 255) >> 8;

    char* ws = (char*)d_ws;
    size_t o = 0;
    auto alloc = [&](size_t bytes) -> void* {
        void* p = ws + o;
        o += (bytes + 255) & ~(size_t)255;
        return p;
    };
    int*          offs   = (int*)   alloc((size_t)(n + 1) * 4);
    float*        di     = (float*) alloc((size_t)n * 4);
    float*        dp     = (float*) alloc((size_t)n * 4);
    ushort*       csrs   = (ushort*)alloc((size_t)E * 2);
    unsigned int* tmp    = (unsigned int*)alloc((size_t)E * 4);
    int*          histT  = (int*)   alloc((size_t)G * 256 * 4);
    int*          coarse = (int*)   alloc(257 * 4);
    __half*       C0     = (__half*)alloc((size_t)n * 32 * 2);   // slice 0 (f 0..31)
    __half*       C1     = (__half*)alloc((size_t)n * 32 * 2);   // slice 1 (f 32..63)
    float*        hA     = (float*) alloc((size_t)n * HF * 4);
    float*        hB     = (float*) alloc((size_t)n * HF * 4);
    float*        z2     = (float*) alloc((size_t)n * 4);

    const int TB = 256;
    int gbN = (n + TB - 1) / TB;
    int gbG = (n + GM_BN - 1) / GM_BN;

    // ---- CSR build (atomic-free, LDS atomics only) ----
    pA_hist   <<<G,  TB, 0, stream>>>(dst, histT, E, G);
    pScan     <<<1,  ST, 0, stream>>>(histT, coarse, G, E);
    pB_scatter<<<G,  TB, 0, stream>>>(src, dst, histT, tmp, E, G);
    pC_build  <<<NB, TB, 0, stream>>>(tmp, coarse, csrs, offs, di, dp, n, E, NB);

    const __half2* S0 = (const __half2*)C0;
    const __half2* S1 = (const __half2*)C1;

    // ---- layer 1 ----
    k_gemm<<<gbG, TB, 0, stream>>>(x, W_in, di, C0, C1, n);
    k_agg<<<AGG_GRID, TB, 0, stream>>>(S0, offs, csrs, di, b_in, 0,  hA, n, 2.0f);
    k_agg<<<AGG_GRID, TB, 0, stream>>>(S1, offs, csrs, di, b_in, 32, hA, n, 2.0f);
    // ---- layer 2 ----
    k_gemm<<<gbG, TB, 0, stream>>>(hA, W_h1, di, C0, C1, n);
    k_agg<<<AGG_GRID, TB, 0, stream>>>(S0, offs, csrs, di, b_h1, 0,  hB, n, 2.0f);
    k_agg<<<AGG_GRID, TB, 0, stream>>>(S1, offs, csrs, di, b_h1, 32, hB, n, 2.0f);
    // ---- layer 3 (agg fused with output projection) ----
    k_gemm<<<gbG, TB, 0, stream>>>(hB, W_h2, di, C0, C1, n);
    k_agg_final<<<AGG_GRID, TB, 0, stream>>>(S0, offs, csrs, di, b_h2, 0,  W_out, dp, z2, n, 0);
    k_agg_final<<<AGG_GRID, TB, 0, stream>>>(S1, offs, csrs, di, b_h2, 32, W_out, dp, z2, n, 1);
    // ---- output layer ----
    k_out<<<gbN, TB, 0, stream>>>(z2, offs, csrs, dp, b_out, out, n);
}

// Round 10
// 277.679 us; speedup vs baseline: 1.6924x; 1.6924x over previous
//
#include <hip/hip_runtime.h>
#include <hip/hip_fp16.h>

// GCN forward: 3x (GCNConv improved + ReLU) + GCNConv(out, 1 feature)
// N=50000, E=1.6M, H=64. CSR via atomic-free MSD counting sort.
// R9 lessons: (a) single-block scan over 256*G entries is latency-bound
// (~1.6us/1000 entries) -> two-level scan (256 parallel bucket scans + one
// 256-wide scan of totals); (b) feature-split + L2-prime REGRESSED agg
// (~70us/layer vs 52) -> revert to single 6.4MB fp16 table, half2 agg.

#define HF 64
#define EPB 16384         // edges per block in passes A/B  (G = ceil(E/EPB))

// ---------------- pass A: coarse histogram (bucket = dst>>8) ----------------
__global__ __launch_bounds__(256) void pA_hist(const int* __restrict__ dst,
                                               int* __restrict__ histT, int E, int G) {
    __shared__ int h[256];
    int g = blockIdx.x, t = threadIdx.x;
    h[t] = 0;
    __syncthreads();
    int beg = g * EPB, end = min(beg + EPB, E);
    for (int i = beg + t; i < end; i += 256) atomicAdd(&h[dst[i] >> 8], 1);
    __syncthreads();
    histT[t * G + g] = h[t];
}

// ---- scan level 1: 256 blocks, bucket b scans its G entries (in-place,
// bucket-relative exclusive) and writes the bucket total ----
__global__ __launch_bounds__(128) void pScan1(int* __restrict__ hist,
                                              int* __restrict__ bsum, int G) {
    __shared__ int sd[128];
    int b = blockIdx.x, t = threadIdx.x;
    int runsum = 0;
    for (int base = 0; base < G; base += 128) {
        int idx = base + t;
        int v = (idx < G) ? hist[b * G + idx] : 0;
        sd[t] = v;
        __syncthreads();
        for (int o = 1; o < 128; o <<= 1) {
            int u = (t >= o) ? sd[t - o] : 0;
            __syncthreads();
            sd[t] += u;
            __syncthreads();
        }
        if (idx < G) hist[b * G + idx] = runsum + sd[t] - v;  // exclusive
        runsum += sd[127];
        __syncthreads();
    }
    if (t == 0) bsum[b] = runsum;
}

// ---- scan level 2: one block scans the 256 bucket totals -> coarse ----
__global__ __launch_bounds__(256) void pScan2(const int* __restrict__ bsum,
                                              int* __restrict__ coarse, int E) {
    __shared__ int sd[256];
    int t = threadIdx.x;
    int v = bsum[t];
    sd[t] = v;
    __syncthreads();
    for (int o = 1; o < 256; o <<= 1) {
        int u = (t >= o) ? sd[t - o] : 0;
        __syncthreads();
        sd[t] += u;
        __syncthreads();
    }
    coarse[t] = sd[t] - v;
    if (t == 255) coarse[256] = E;
}

// ---------------- pass B: coarse scatter (LDS cursors) ----------------
__global__ __launch_bounds__(256) void pB_scatter(const int* __restrict__ src,
                                                  const int* __restrict__ dst,
                                                  const int* __restrict__ histT,
                                                  const int* __restrict__ coarse,
                                                  unsigned int* __restrict__ tmp,
                                                  int E, int G) {
    __shared__ int cur[256];
    int g = blockIdx.x, t = threadIdx.x;
    cur[t] = coarse[t] + histT[t * G + g];
    __syncthreads();
    int beg = g * EPB, end = min(beg + EPB, E);
    for (int i = beg + t; i < end; i += 256) {
        int d = dst[i], s = src[i];
        int pos = atomicAdd(&cur[d >> 8], 1);
        tmp[pos] = ((unsigned int)(d & 255) << 16) | (unsigned int)(s & 0xFFFF);
    }
}

// ---------------- pass C: per-bucket fine counting sort + CSR metadata -------
__global__ __launch_bounds__(256) void pC_build(const unsigned int* __restrict__ tmp,
                                                const int* __restrict__ coarse,
                                                ushort* __restrict__ csrs,
                                                int* __restrict__ offs,
                                                float* __restrict__ di,
                                                float* __restrict__ dp,
                                                int n, int E, int NB) {
    __shared__ int hist[256];
    __shared__ int cur[256];
    __shared__ int scanbuf[256];
    int b = blockIdx.x, t = threadIdx.x;
    int beg = coarse[b], end = coarse[b + 1];
    hist[t] = 0;
    __syncthreads();
    for (int i = beg + t; i < end; i += 256) atomicAdd(&hist[tmp[i] >> 16], 1);
    __syncthreads();
    int v = hist[t];
    scanbuf[t] = v;
    __syncthreads();
    for (int o = 1; o < 256; o <<= 1) {
        int u = (t >= o) ? scanbuf[t - o] : 0;
        __syncthreads();
        scanbuf[t] += u;
        __syncthreads();
    }
    int excl = scanbuf[t] - v;
    cur[t] = beg + excl;
    int d = (b << 8) + t;
    if (d < n) {
        offs[d] = beg + excl;
        float df = (float)v;
        di[d] = rsqrtf(df + 2.0f);   // improved=True: self-loop weight 2
        dp[d] = rsqrtf(df + 1.0f);   // output layer: improved=False
    }
    if (b == NB - 1 && t == 0) offs[n] = E;
    __syncthreads();
    for (int i = beg + t; i < end; i += 256) {
        unsigned int e = tmp[i];
        int pos = atomicAdd(&cur[e >> 16], 1);
        csrs[pos] = (ushort)(e & 0xFFFFu);
    }
}

// ---- dense GEMM: C[n,64] = di[n] * (A[n,64] @ W[64,64]), C in fp16 ----------
#define GM_BN 128
__global__ __launch_bounds__(256) void k_gemm(const float* __restrict__ A,
                                              const float* __restrict__ W,
                                              const float* __restrict__ di,
                                              __half* __restrict__ C, int n) {
    __shared__ float xT[64][132];
    __shared__ float Wl[64][64];
    int tid = threadIdx.x;
    int nb = blockIdx.x * GM_BN;

    for (int r = 0; r < 4; ++r) {
        int q = tid + 256 * r;
        int row = q >> 4, c4 = (q & 15) << 2;
        *(float4*)&Wl[row][c4] = *(const float4*)&W[row * 64 + c4];
    }
    for (int r = 0; r < 8; ++r) {
        int q = tid + 256 * r;
        int nl = q >> 4, k0 = (q & 15) << 2;
        float4 v = make_float4(0.f, 0.f, 0.f, 0.f);
        if (nb + nl < n) v = *(const float4*)&A[(size_t)(nb + nl) * HF + k0];
        xT[k0 + 0][nl] = v.x; xT[k0 + 1][nl] = v.y;
        xT[k0 + 2][nl] = v.z; xT[k0 + 3][nl] = v.w;
    }
    __syncthreads();

    int tx = tid & 7;
    int ty = tid >> 3;
    int f0 = tx * 8, n0 = ty * 4;
    float acc[4][8];
#pragma unroll
    for (int i = 0; i < 4; ++i)
#pragma unroll
        for (int j = 0; j < 8; ++j) acc[i][j] = 0.f;

#pragma unroll 4
    for (int k = 0; k < 64; ++k) {
        float4 xa = *(float4*)&xT[k][n0];
        float4 wa = *(float4*)&Wl[k][f0];
        float4 wb = *(float4*)&Wl[k][f0 + 4];
        float xs[4] = {xa.x, xa.y, xa.z, xa.w};
        float wsv[8] = {wa.x, wa.y, wa.z, wa.w, wb.x, wb.y, wb.z, wb.w};
#pragma unroll
        for (int i = 0; i < 4; ++i)
#pragma unroll
            for (int j = 0; j < 8; ++j) acc[i][j] += xs[i] * wsv[j];
    }

#pragma unroll
    for (int i = 0; i < 4; ++i) {
        int nn = nb + n0 + i;
        if (nn < n) {
            float dr = di[nn];                  // fold edge weight into table
            union { __half h[8]; float4 f4; } u;
#pragma unroll
            for (int j = 0; j < 8; ++j) u.h[j] = __float2half(acc[i][j] * dr);
            *(float4*)&C[(size_t)nn * HF + f0] = u.f4;
        }
    }
}

// ---------------- agg: one wave per node, half-wave per edge -----------------
// lanes: half = lane>>5 (edge slot), fh = lane&31 (feature pair 2fh,2fh+1)
__device__ __forceinline__ void agg_edges2(const __half2* __restrict__ P2,
                                           const ushort* __restrict__ csrs,
                                           int beg, int deg, int half, int fh,
                                           float& A0, float& A1) {
    float a0 = 0.f, a1 = 0.f;
    int pairs = deg >> 1;
    int e = beg + half;
    int chunks = pairs >> 1;
    for (int c = 0; c < chunks; ++c, e += 4) {
        int s0 = csrs[e];
        int s1 = csrs[e + 2];
        float2 v0 = __half22float2(P2[(size_t)s0 * 32 + fh]);
        float2 v1 = __half22float2(P2[(size_t)s1 * 32 + fh]);
        a0 += v0.x; a1 += v0.y;
        a0 += v1.x; a1 += v1.y;
    }
    if (pairs & 1) {
        int s = csrs[e];
        float2 v = __half22float2(P2[(size_t)s * 32 + fh]);
        a0 += v.x; a1 += v.y;
    }
    if ((deg & 1) && half == 0) {
        int s = csrs[beg + deg - 1];
        float2 v = __half22float2(P2[(size_t)s * 32 + fh]);
        a0 += v.x; a1 += v.y;
    }
    a0 += __shfl_xor(a0, 32);
    a1 += __shfl_xor(a1, 32);
    A0 = a0; A1 = a1;
}

__global__ __launch_bounds__(256) void k_agg(const __half2* __restrict__ P2,
                      const int* __restrict__ offs, const ushort* __restrict__ csrs,
                      const float* __restrict__ di, const float* __restrict__ bias,
                      float* __restrict__ out, int n, float fill) {
    int wid = (blockIdx.x * blockDim.x + threadIdx.x) >> 6;
    if (wid >= n) return;
    int lane = threadIdx.x & 63;
    int half = lane >> 5, fh = lane & 31;
    int beg = offs[wid], deg = offs[wid + 1] - beg;
    float a0, a1;
    agg_edges2(P2, csrs, beg, deg, half, fh, a0, a1);
    float dw = di[wid];
    float2 self = __half22float2(P2[(size_t)wid * 32 + fh]);
    a0 = fmaxf(dw * (a0 + fill * self.x) + bias[2 * fh + 0], 0.f);
    a1 = fmaxf(dw * (a1 + fill * self.y) + bias[2 * fh + 1], 0.f);
    if (half == 0) {
        float* op = &out[(size_t)wid * HF + 2 * fh];
        __builtin_nontemporal_store(a0, op);
        __builtin_nontemporal_store(a1, op + 1);
    }
}

// layer-3 agg fused with output projection: z2 = dp * (relu(agg+b) . Wout)
__global__ __launch_bounds__(256) void k_agg_final(const __half2* __restrict__ P2,
                      const int* __restrict__ offs, const ushort* __restrict__ csrs,
                      const float* __restrict__ di, const float* __restrict__ bias,
                      const float* __restrict__ Wout, const float* __restrict__ dp,
                      float* __restrict__ z2, int n) {
    int wid = (blockIdx.x * blockDim.x + threadIdx.x) >> 6;
    if (wid >= n) return;
    int lane = threadIdx.x & 63;
    int half = lane >> 5, fh = lane & 31;
    int beg = offs[wid], deg = offs[wid + 1] - beg;
    float a0, a1;
    agg_edges2(P2, csrs, beg, deg, half, fh, a0, a1);
    float dw = di[wid];
    float2 self = __half22float2(P2[(size_t)wid * 32 + fh]);
    a0 = fmaxf(dw * (a0 + 2.0f * self.x) + bias[2 * fh + 0], 0.f);
    a1 = fmaxf(dw * (a1 + 2.0f * self.y) + bias[2 * fh + 1], 0.f);
    float v = a0 * Wout[2 * fh] + a1 * Wout[2 * fh + 1];
#pragma unroll
    for (int o = 16; o > 0; o >>= 1) v += __shfl_down(v, o, 32);
    if (lane == 0) z2[wid] = v * dp[wid];
}

// out[n] = dp[n] * (sum_e z2[src] + z2[n]) + b_out
__global__ void k_out(const float* __restrict__ z2, const int* __restrict__ offs,
                      const ushort* __restrict__ csrs, const float* __restrict__ dp,
                      const float* __restrict__ bout, float* __restrict__ out, int n) {
    int i = blockIdx.x * blockDim.x + threadIdx.x;
    if (i >= n) return;
    int beg = offs[i], end = offs[i + 1];
    float acc = 0.f;
    for (int e = beg; e < end; ++e) acc += z2[csrs[e]];
    out[i] = dp[i] * (acc + z2[i]) + bout[0];
}

extern "C" void kernel_launch(void* const* d_in, const int* in_sizes, int n_in,
                              void* d_out, int out_size, void* d_ws, size_t ws_size,
                              hipStream_t stream) {
    const float* x    = (const float*)d_in[0];
    const int*   ei   = (const int*)d_in[1];
    const float* W_in = (const float*)d_in[2];
    const float* b_in = (const float*)d_in[3];
    const float* W_h1 = (const float*)d_in[4];
    const float* b_h1 = (const float*)d_in[5];
    const float* W_h2 = (const float*)d_in[6];
    const float* b_h2 = (const float*)d_in[7];
    const float* W_out= (const float*)d_in[8];
    const float* b_out= (const float*)d_in[9];
    float* out = (float*)d_out;

    const int n = in_sizes[0] / HF;        // 50000 (< 65536: ushort CSR ok)
    const int E = in_sizes[1] / 2;         // 1.6M
    const int* src = ei;
    const int* dst = ei + E;

    const int G  = (E + EPB - 1) / EPB;    // 98
    const int NB = (n + 255) >> 8;

    char* ws = (char*)d_ws;
    size_t o = 0;
    auto alloc = [&](size_t bytes) -> void* {
        void* p = ws + o;
        o += (bytes + 255) & ~(size_t)255;
        return p;
    };
    int*          offs   = (int*)   alloc((size_t)(n + 1) * 4);
    float*        di     = (float*) alloc((size_t)n * 4);
    float*        dp     = (float*) alloc((size_t)n * 4);
    ushort*       csrs   = (ushort*)alloc((size_t)E * 2);
    unsigned int* tmp    = (unsigned int*)alloc((size_t)E * 4);
    int*          histT  = (int*)   alloc((size_t)G * 256 * 4);
    int*          bsum   = (int*)   alloc(256 * 4);
    int*          coarse = (int*)   alloc(257 * 4);
    __half*       hW     = (__half*)alloc((size_t)n * HF * 2);   // fp16 P' table
    float*        hA     = (float*) alloc((size_t)n * HF * 4);
    float*        hB     = (float*) alloc((size_t)n * HF * 4);
    float*        z2     = (float*) alloc((size_t)n * 4);

    const int TB = 256;
    int gbN = (n + TB - 1) / TB;
    int gbW = (n * 64 + TB - 1) / TB;
    int gbG = (n + GM_BN - 1) / GM_BN;

    // ---- CSR build (atomic-free, LDS atomics only; two-level scan) ----
    pA_hist   <<<G,   TB, 0, stream>>>(dst, histT, E, G);
    pScan1    <<<256, 128, 0, stream>>>(histT, bsum, G);
    pScan2    <<<1,   TB, 0, stream>>>(bsum, coarse, E);
    pB_scatter<<<G,   TB, 0, stream>>>(src, dst, histT, coarse, tmp, E, G);
    pC_build  <<<NB,  TB, 0, stream>>>(tmp, coarse, csrs, offs, di, dp, n, E, NB);

    const __half2* hW2 = (const __half2*)hW;

    // ---- layer 1 ----
    k_gemm<<<gbG, TB, 0, stream>>>(x, W_in, di, hW, n);
    k_agg<<<gbW, TB, 0, stream>>>(hW2, offs, csrs, di, b_in, hA, n, 2.0f);
    // ---- layer 2 ----
    k_gemm<<<gbG, TB, 0, stream>>>(hA, W_h1, di, hW, n);
    k_agg<<<gbW, TB, 0, stream>>>(hW2, offs, csrs, di, b_h1, hB, n, 2.0f);
    // ---- layer 3 (agg fused with output projection) ----
    k_gemm<<<gbG, TB, 0, stream>>>(hB, W_h2, di, hW, n);
    k_agg_final<<<gbW, TB, 0, stream>>>(hW2, offs, csrs, di, b_h2, W_out, dp, z2, n);
    // ---- output layer ----
    k_out<<<gbN, TB, 0, stream>>>(z2, offs, csrs, dp, b_out, out, n);
}

// Round 11
// 243.245 us; speedup vs baseline: 1.9320x; 1.1416x over previous
//
#include <hip/hip_runtime.h>
#include <hip/hip_fp16.h>

// GCN forward: 3x (GCNConv improved + ReLU) + GCNConv(out, 1 feature)
// N=50000, E=1.6M, H=64. CSR via atomic-free MSD counting sort + 2-level scan.
// Agg: fp16 P' table (weights folded), half2 lanes. R10 profile: FETCH = 8 XCD
// x 6.4MB compulsory fills at ~1TB/s => per-CU miss-MLP bound. This round:
// unroll edge loop to 4 rows in flight per half-wave (VGPR 12 -> ~24, still
// full occupancy; R5's failed unroll was 40 VGPR -> 52% occ).

#define HF 64
#define EPB 16384         // edges per block in passes A/B  (G = ceil(E/EPB))

// ---------------- pass A: coarse histogram (bucket = dst>>8) ----------------
__global__ __launch_bounds__(256) void pA_hist(const int* __restrict__ dst,
                                               int* __restrict__ histT, int E, int G) {
    __shared__ int h[256];
    int g = blockIdx.x, t = threadIdx.x;
    h[t] = 0;
    __syncthreads();
    int beg = g * EPB, end = min(beg + EPB, E);
    for (int i = beg + t; i < end; i += 256) atomicAdd(&h[dst[i] >> 8], 1);
    __syncthreads();
    histT[t * G + g] = h[t];
}

// ---- scan level 1: 256 blocks, bucket b scans its G entries ----
__global__ __launch_bounds__(128) void pScan1(int* __restrict__ hist,
                                              int* __restrict__ bsum, int G) {
    __shared__ int sd[128];
    int b = blockIdx.x, t = threadIdx.x;
    int runsum = 0;
    for (int base = 0; base < G; base += 128) {
        int idx = base + t;
        int v = (idx < G) ? hist[b * G + idx] : 0;
        sd[t] = v;
        __syncthreads();
        for (int o = 1; o < 128; o <<= 1) {
            int u = (t >= o) ? sd[t - o] : 0;
            __syncthreads();
            sd[t] += u;
            __syncthreads();
        }
        if (idx < G) hist[b * G + idx] = runsum + sd[t] - v;  // exclusive
        runsum += sd[127];
        __syncthreads();
    }
    if (t == 0) bsum[b] = runsum;
}

// ---- scan level 2: one block scans the 256 bucket totals -> coarse ----
__global__ __launch_bounds__(256) void pScan2(const int* __restrict__ bsum,
                                              int* __restrict__ coarse, int E) {
    __shared__ int sd[256];
    int t = threadIdx.x;
    int v = bsum[t];
    sd[t] = v;
    __syncthreads();
    for (int o = 1; o < 256; o <<= 1) {
        int u = (t >= o) ? sd[t - o] : 0;
        __syncthreads();
        sd[t] += u;
        __syncthreads();
    }
    coarse[t] = sd[t] - v;
    if (t == 255) coarse[256] = E;
}

// ---------------- pass B: coarse scatter (LDS cursors) ----------------
__global__ __launch_bounds__(256) void pB_scatter(const int* __restrict__ src,
                                                  const int* __restrict__ dst,
                                                  const int* __restrict__ histT,
                                                  const int* __restrict__ coarse,
                                                  unsigned int* __restrict__ tmp,
                                                  int E, int G) {
    __shared__ int cur[256];
    int g = blockIdx.x, t = threadIdx.x;
    cur[t] = coarse[t] + histT[t * G + g];
    __syncthreads();
    int beg = g * EPB, end = min(beg + EPB, E);
    for (int i = beg + t; i < end; i += 256) {
        int d = dst[i], s = src[i];
        int pos = atomicAdd(&cur[d >> 8], 1);
        tmp[pos] = ((unsigned int)(d & 255) << 16) | (unsigned int)(s & 0xFFFF);
    }
}

// ---------------- pass C: per-bucket fine counting sort + CSR metadata -------
__global__ __launch_bounds__(256) void pC_build(const unsigned int* __restrict__ tmp,
                                                const int* __restrict__ coarse,
                                                ushort* __restrict__ csrs,
                                                int* __restrict__ offs,
                                                float* __restrict__ di,
                                                float* __restrict__ dp,
                                                int n, int E, int NB) {
    __shared__ int hist[256];
    __shared__ int cur[256];
    __shared__ int scanbuf[256];
    int b = blockIdx.x, t = threadIdx.x;
    int beg = coarse[b], end = coarse[b + 1];
    hist[t] = 0;
    __syncthreads();
    for (int i = beg + t; i < end; i += 256) atomicAdd(&hist[tmp[i] >> 16], 1);
    __syncthreads();
    int v = hist[t];
    scanbuf[t] = v;
    __syncthreads();
    for (int o = 1; o < 256; o <<= 1) {
        int u = (t >= o) ? scanbuf[t - o] : 0;
        __syncthreads();
        scanbuf[t] += u;
        __syncthreads();
    }
    int excl = scanbuf[t] - v;
    cur[t] = beg + excl;
    int d = (b << 8) + t;
    if (d < n) {
        offs[d] = beg + excl;
        float df = (float)v;
        di[d] = rsqrtf(df + 2.0f);   // improved=True: self-loop weight 2
        dp[d] = rsqrtf(df + 1.0f);   // output layer: improved=False
    }
    if (b == NB - 1 && t == 0) offs[n] = E;
    __syncthreads();
    for (int i = beg + t; i < end; i += 256) {
        unsigned int e = tmp[i];
        int pos = atomicAdd(&cur[e >> 16], 1);
        csrs[pos] = (ushort)(e & 0xFFFFu);
    }
}

// ---- dense GEMM: C[n,64] = di[n] * (A[n,64] @ W[64,64]), C in fp16 ----------
#define GM_BN 128
__global__ __launch_bounds__(256) void k_gemm(const float* __restrict__ A,
                                              const float* __restrict__ W,
                                              const float* __restrict__ di,
                                              __half* __restrict__ C, int n) {
    __shared__ float xT[64][132];
    __shared__ float Wl[64][64];
    int tid = threadIdx.x;
    int nb = blockIdx.x * GM_BN;

    for (int r = 0; r < 4; ++r) {
        int q = tid + 256 * r;
        int row = q >> 4, c4 = (q & 15) << 2;
        *(float4*)&Wl[row][c4] = *(const float4*)&W[row * 64 + c4];
    }
    for (int r = 0; r < 8; ++r) {
        int q = tid + 256 * r;
        int nl = q >> 4, k0 = (q & 15) << 2;
        float4 v = make_float4(0.f, 0.f, 0.f, 0.f);
        if (nb + nl < n) v = *(const float4*)&A[(size_t)(nb + nl) * HF + k0];
        xT[k0 + 0][nl] = v.x; xT[k0 + 1][nl] = v.y;
        xT[k0 + 2][nl] = v.z; xT[k0 + 3][nl] = v.w;
    }
    __syncthreads();

    int tx = tid & 7;
    int ty = tid >> 3;
    int f0 = tx * 8, n0 = ty * 4;
    float acc[4][8];
#pragma unroll
    for (int i = 0; i < 4; ++i)
#pragma unroll
        for (int j = 0; j < 8; ++j) acc[i][j] = 0.f;

#pragma unroll 4
    for (int k = 0; k < 64; ++k) {
        float4 xa = *(float4*)&xT[k][n0];
        float4 wa = *(float4*)&Wl[k][f0];
        float4 wb = *(float4*)&Wl[k][f0 + 4];
        float xs[4] = {xa.x, xa.y, xa.z, xa.w};
        float wsv[8] = {wa.x, wa.y, wa.z, wa.w, wb.x, wb.y, wb.z, wb.w};
#pragma unroll
        for (int i = 0; i < 4; ++i)
#pragma unroll
            for (int j = 0; j < 8; ++j) acc[i][j] += xs[i] * wsv[j];
    }

#pragma unroll
    for (int i = 0; i < 4; ++i) {
        int nn = nb + n0 + i;
        if (nn < n) {
            float dr = di[nn];                  // fold edge weight into table
            union { __half h[8]; float4 f4; } u;
#pragma unroll
            for (int j = 0; j < 8; ++j) u.h[j] = __float2half(acc[i][j] * dr);
            *(float4*)&C[(size_t)nn * HF + f0] = u.f4;
        }
    }
}

// ---------------- agg: one wave per node, half-wave per edge -----------------
// lanes: half = lane>>5 (edge slot), fh = lane&31 (feature pair 2fh,2fh+1)
// unroll: 4 rows in flight per half-wave (8 edges/wave-iteration)
__device__ __forceinline__ void agg_edges2(const __half2* __restrict__ P2,
                                           const ushort* __restrict__ csrs,
                                           int beg, int deg, int half, int fh,
                                           float& A0, float& A1) {
    float a0 = 0.f, a1 = 0.f, b0 = 0.f, b1 = 0.f;
    int pairs = deg >> 1;           // each pair = 2 edges (one per half)
    int e = beg + half;
    int chunks = pairs >> 2;        // 4 pairs per iteration
    for (int c = 0; c < chunks; ++c, e += 8) {
        int s0 = csrs[e];
        int s1 = csrs[e + 2];
        int s2 = csrs[e + 4];
        int s3 = csrs[e + 6];
        float2 v0 = __half22float2(P2[(size_t)s0 * 32 + fh]);
        float2 v1 = __half22float2(P2[(size_t)s1 * 32 + fh]);
        float2 v2 = __half22float2(P2[(size_t)s2 * 32 + fh]);
        float2 v3 = __half22float2(P2[(size_t)s3 * 32 + fh]);
        a0 += v0.x; a1 += v0.y;
        b0 += v1.x; b1 += v1.y;
        a0 += v2.x; a1 += v2.y;
        b0 += v3.x; b1 += v3.y;
    }
    for (int r = pairs & 3; r > 0; --r, e += 2) {
        int s = csrs[e];
        float2 v = __half22float2(P2[(size_t)s * 32 + fh]);
        a0 += v.x; a1 += v.y;
    }
    if ((deg & 1) && half == 0) {
        int s = csrs[beg + deg - 1];
        float2 v = __half22float2(P2[(size_t)s * 32 + fh]);
        a0 += v.x; a1 += v.y;
    }
    a0 += b0; a1 += b1;
    a0 += __shfl_xor(a0, 32);
    a1 += __shfl_xor(a1, 32);
    A0 = a0; A1 = a1;
}

__global__ __launch_bounds__(256) void k_agg(const __half2* __restrict__ P2,
                      const int* __restrict__ offs, const ushort* __restrict__ csrs,
                      const float* __restrict__ di, const float* __restrict__ bias,
                      float* __restrict__ out, int n, float fill) {
    int wid = (blockIdx.x * blockDim.x + threadIdx.x) >> 6;
    if (wid >= n) return;
    int lane = threadIdx.x & 63;
    int half = lane >> 5, fh = lane & 31;
    int beg = offs[wid], deg = offs[wid + 1] - beg;
    float a0, a1;
    agg_edges2(P2, csrs, beg, deg, half, fh, a0, a1);
    float dw = di[wid];
    float2 self = __half22float2(P2[(size_t)wid * 32 + fh]);
    a0 = fmaxf(dw * (a0 + fill * self.x) + bias[2 * fh + 0], 0.f);
    a1 = fmaxf(dw * (a1 + fill * self.y) + bias[2 * fh + 1], 0.f);
    if (half == 0) {
        float* op = &out[(size_t)wid * HF + 2 * fh];
        __builtin_nontemporal_store(a0, op);
        __builtin_nontemporal_store(a1, op + 1);
    }
}

// layer-3 agg fused with output projection: z2 = dp * (relu(agg+b) . Wout)
__global__ __launch_bounds__(256) void k_agg_final(const __half2* __restrict__ P2,
                      const int* __restrict__ offs, const ushort* __restrict__ csrs,
                      const float* __restrict__ di, const float* __restrict__ bias,
                      const float* __restrict__ Wout, const float* __restrict__ dp,
                      float* __restrict__ z2, int n) {
    int wid = (blockIdx.x * blockDim.x + threadIdx.x) >> 6;
    if (wid >= n) return;
    int lane = threadIdx.x & 63;
    int half = lane >> 5, fh = lane & 31;
    int beg = offs[wid], deg = offs[wid + 1] - beg;
    float a0, a1;
    agg_edges2(P2, csrs, beg, deg, half, fh, a0, a1);
    float dw = di[wid];
    float2 self = __half22float2(P2[(size_t)wid * 32 + fh]);
    a0 = fmaxf(dw * (a0 + 2.0f * self.x) + bias[2 * fh + 0], 0.f);
    a1 = fmaxf(dw * (a1 + 2.0f * self.y) + bias[2 * fh + 1], 0.f);
    float v = a0 * Wout[2 * fh] + a1 * Wout[2 * fh + 1];
#pragma unroll
    for (int o = 16; o > 0; o >>= 1) v += __shfl_down(v, o, 32);
    if (lane == 0) z2[wid] = v * dp[wid];
}

// out[n] = dp[n] * (sum_e z2[src] + z2[n]) + b_out
__global__ void k_out(const float* __restrict__ z2, const int* __restrict__ offs,
                      const ushort* __restrict__ csrs, const float* __restrict__ dp,
                      const float* __restrict__ bout, float* __restrict__ out, int n) {
    int i = blockIdx.x * blockDim.x + threadIdx.x;
    if (i >= n) return;
    int beg = offs[i], end = offs[i + 1];
    float acc = 0.f;
    for (int e = beg; e < end; ++e) acc += z2[csrs[e]];
    out[i] = dp[i] * (acc + z2[i]) + bout[0];
}

extern "C" void kernel_launch(void* const* d_in, const int* in_sizes, int n_in,
                              void* d_out, int out_size, void* d_ws, size_t ws_size,
                              hipStream_t stream) {
    const float* x    = (const float*)d_in[0];
    const int*   ei   = (const int*)d_in[1];
    const float* W_in = (const float*)d_in[2];
    const float* b_in = (const float*)d_in[3];
    const float* W_h1 = (const float*)d_in[4];
    const float* b_h1 = (const float*)d_in[5];
    const float* W_h2 = (const float*)d_in[6];
    const float* b_h2 = (const float*)d_in[7];
    const float* W_out= (const float*)d_in[8];
    const float* b_out= (const float*)d_in[9];
    float* out = (float*)d_out;

    const int n = in_sizes[0] / HF;        // 50000 (< 65536: ushort CSR ok)
    const int E = in_sizes[1] / 2;         // 1.6M
    const int* src = ei;
    const int* dst = ei + E;

    const int G  = (E + EPB - 1) / EPB;    // 98
    const int NB = (n + 255) >> 8;

    char* ws = (char*)d_ws;
    size_t o = 0;
    auto alloc = [&](size_t bytes) -> void* {
        void* p = ws + o;
        o += (bytes + 255) & ~(size_t)255;
        return p;
    };
    int*          offs   = (int*)   alloc((size_t)(n + 1) * 4);
    float*        di     = (float*) alloc((size_t)n * 4);
    float*        dp     = (float*) alloc((size_t)n * 4);
    ushort*       csrs   = (ushort*)alloc((size_t)E * 2);
    unsigned int* tmp    = (unsigned int*)alloc((size_t)E * 4);
    int*          histT  = (int*)   alloc((size_t)G * 256 * 4);
    int*          bsum   = (int*)   alloc(256 * 4);
    int*          coarse = (int*)   alloc(257 * 4);
    __half*       hW     = (__half*)alloc((size_t)n * HF * 2);   // fp16 P' table
    float*        hA     = (float*) alloc((size_t)n * HF * 4);
    float*        hB     = (float*) alloc((size_t)n * HF * 4);
    float*        z2     = (float*) alloc((size_t)n * 4);

    const int TB = 256;
    int gbN = (n + TB - 1) / TB;
    int gbW = (n * 64 + TB - 1) / TB;
    int gbG = (n + GM_BN - 1) / GM_BN;

    // ---- CSR build (atomic-free, LDS atomics only; two-level scan) ----
    pA_hist   <<<G,   TB, 0, stream>>>(dst, histT, E, G);
    pScan1    <<<256, 128, 0, stream>>>(histT, bsum, G);
    pScan2    <<<1,   TB, 0, stream>>>(bsum, coarse, E);
    pB_scatter<<<G,   TB, 0, stream>>>(src, dst, histT, coarse, tmp, E, G);
    pC_build  <<<NB,  TB, 0, stream>>>(tmp, coarse, csrs, offs, di, dp, n, E, NB);

    const __half2* hW2 = (const __half2*)hW;

    // ---- layer 1 ----
    k_gemm<<<gbG, TB, 0, stream>>>(x, W_in, di, hW, n);
    k_agg<<<gbW, TB, 0, stream>>>(hW2, offs, csrs, di, b_in, hA, n, 2.0f);
    // ---- layer 2 ----
    k_gemm<<<gbG, TB, 0, stream>>>(hA, W_h1, di, hW, n);
    k_agg<<<gbW, TB, 0, stream>>>(hW2, offs, csrs, di, b_h1, hB, n, 2.0f);
    // ---- layer 3 (agg fused with output projection) ----
    k_gemm<<<gbG, TB, 0, stream>>>(hB, W_h2, di, hW, n);
    k_agg_final<<<gbW, TB, 0, stream>>>(hW2, offs, csrs, di, b_h2, W_out, dp, z2, n);
    // ---- output layer ----
    k_out<<<gbN, TB, 0, stream>>>(z2, offs, csrs, dp, b_out, out, n);
}

// Round 12
// 240.505 us; speedup vs baseline: 1.9540x; 1.0114x over previous
//
#include <hip/hip_runtime.h>
#include <hip/hip_fp16.h>

// GCN forward: 3x (GCNConv improved + ReLU) + GCNConv(out, 1 feature)
// N=50000, E=1.6M, H=64. CSR via atomic-free MSD counting sort + 2-level scan.
// Agg: fp16 P' table (weights folded), half2 lanes. R10->R11: unroll-4 MLP
// gained 12us/agg (miss-MLP bound confirmed). This round: unroll-8 (16 edges
// in flight per wave). ~40 VGPR, still < 64-VGPR full-occupancy threshold.
// k_out: 16 lanes/node + shuffle reduce (was serial 32-iter loop).

#define HF 64
#define EPB 16384         // edges per block in passes A/B  (G = ceil(E/EPB))

// ---------------- pass A: coarse histogram (bucket = dst>>8) ----------------
__global__ __launch_bounds__(256) void pA_hist(const int* __restrict__ dst,
                                               int* __restrict__ histT, int E, int G) {
    __shared__ int h[256];
    int g = blockIdx.x, t = threadIdx.x;
    h[t] = 0;
    __syncthreads();
    int beg = g * EPB, end = min(beg + EPB, E);
    for (int i = beg + t; i < end; i += 256) atomicAdd(&h[dst[i] >> 8], 1);
    __syncthreads();
    histT[t * G + g] = h[t];
}

// ---- scan level 1: 256 blocks, bucket b scans its G entries ----
__global__ __launch_bounds__(128) void pScan1(int* __restrict__ hist,
                                              int* __restrict__ bsum, int G) {
    __shared__ int sd[128];
    int b = blockIdx.x, t = threadIdx.x;
    int runsum = 0;
    for (int base = 0; base < G; base += 128) {
        int idx = base + t;
        int v = (idx < G) ? hist[b * G + idx] : 0;
        sd[t] = v;
        __syncthreads();
        for (int o = 1; o < 128; o <<= 1) {
            int u = (t >= o) ? sd[t - o] : 0;
            __syncthreads();
            sd[t] += u;
            __syncthreads();
        }
        if (idx < G) hist[b * G + idx] = runsum + sd[t] - v;  // exclusive
        runsum += sd[127];
        __syncthreads();
    }
    if (t == 0) bsum[b] = runsum;
}

// ---- scan level 2: one block scans the 256 bucket totals -> coarse ----
__global__ __launch_bounds__(256) void pScan2(const int* __restrict__ bsum,
                                              int* __restrict__ coarse, int E) {
    __shared__ int sd[256];
    int t = threadIdx.x;
    int v = bsum[t];
    sd[t] = v;
    __syncthreads();
    for (int o = 1; o < 256; o <<= 1) {
        int u = (t >= o) ? sd[t - o] : 0;
        __syncthreads();
        sd[t] += u;
        __syncthreads();
    }
    coarse[t] = sd[t] - v;
    if (t == 255) coarse[256] = E;
}

// ---------------- pass B: coarse scatter (LDS cursors) ----------------
__global__ __launch_bounds__(256) void pB_scatter(const int* __restrict__ src,
                                                  const int* __restrict__ dst,
                                                  const int* __restrict__ histT,
                                                  const int* __restrict__ coarse,
                                                  unsigned int* __restrict__ tmp,
                                                  int E, int G) {
    __shared__ int cur[256];
    int g = blockIdx.x, t = threadIdx.x;
    cur[t] = coarse[t] + histT[t * G + g];
    __syncthreads();
    int beg = g * EPB, end = min(beg + EPB, E);
    for (int i = beg + t; i < end; i += 256) {
        int d = dst[i], s = src[i];
        int pos = atomicAdd(&cur[d >> 8], 1);
        tmp[pos] = ((unsigned int)(d & 255) << 16) | (unsigned int)(s & 0xFFFF);
    }
}

// ---------------- pass C: per-bucket fine counting sort + CSR metadata -------
__global__ __launch_bounds__(256) void pC_build(const unsigned int* __restrict__ tmp,
                                                const int* __restrict__ coarse,
                                                ushort* __restrict__ csrs,
                                                int* __restrict__ offs,
                                                float* __restrict__ di,
                                                float* __restrict__ dp,
                                                int n, int E, int NB) {
    __shared__ int hist[256];
    __shared__ int cur[256];
    __shared__ int scanbuf[256];
    int b = blockIdx.x, t = threadIdx.x;
    int beg = coarse[b], end = coarse[b + 1];
    hist[t] = 0;
    __syncthreads();
    for (int i = beg + t; i < end; i += 256) atomicAdd(&hist[tmp[i] >> 16], 1);
    __syncthreads();
    int v = hist[t];
    scanbuf[t] = v;
    __syncthreads();
    for (int o = 1; o < 256; o <<= 1) {
        int u = (t >= o) ? scanbuf[t - o] : 0;
        __syncthreads();
        scanbuf[t] += u;
        __syncthreads();
    }
    int excl = scanbuf[t] - v;
    cur[t] = beg + excl;
    int d = (b << 8) + t;
    if (d < n) {
        offs[d] = beg + excl;
        float df = (float)v;
        di[d] = rsqrtf(df + 2.0f);   // improved=True: self-loop weight 2
        dp[d] = rsqrtf(df + 1.0f);   // output layer: improved=False
    }
    if (b == NB - 1 && t == 0) offs[n] = E;
    __syncthreads();
    for (int i = beg + t; i < end; i += 256) {
        unsigned int e = tmp[i];
        int pos = atomicAdd(&cur[e >> 16], 1);
        csrs[pos] = (ushort)(e & 0xFFFFu);
    }
}

// ---- dense GEMM: C[n,64] = di[n] * (A[n,64] @ W[64,64]), C in fp16 ----------
#define GM_BN 128
__global__ __launch_bounds__(256) void k_gemm(const float* __restrict__ A,
                                              const float* __restrict__ W,
                                              const float* __restrict__ di,
                                              __half* __restrict__ C, int n) {
    __shared__ float xT[64][132];
    __shared__ float Wl[64][64];
    int tid = threadIdx.x;
    int nb = blockIdx.x * GM_BN;

    for (int r = 0; r < 4; ++r) {
        int q = tid + 256 * r;
        int row = q >> 4, c4 = (q & 15) << 2;
        *(float4*)&Wl[row][c4] = *(const float4*)&W[row * 64 + c4];
    }
    for (int r = 0; r < 8; ++r) {
        int q = tid + 256 * r;
        int nl = q >> 4, k0 = (q & 15) << 2;
        float4 v = make_float4(0.f, 0.f, 0.f, 0.f);
        if (nb + nl < n) v = *(const float4*)&A[(size_t)(nb + nl) * HF + k0];
        xT[k0 + 0][nl] = v.x; xT[k0 + 1][nl] = v.y;
        xT[k0 + 2][nl] = v.z; xT[k0 + 3][nl] = v.w;
    }
    __syncthreads();

    int tx = tid & 7;
    int ty = tid >> 3;
    int f0 = tx * 8, n0 = ty * 4;
    float acc[4][8];
#pragma unroll
    for (int i = 0; i < 4; ++i)
#pragma unroll
        for (int j = 0; j < 8; ++j) acc[i][j] = 0.f;

#pragma unroll 4
    for (int k = 0; k < 64; ++k) {
        float4 xa = *(float4*)&xT[k][n0];
        float4 wa = *(float4*)&Wl[k][f0];
        float4 wb = *(float4*)&Wl[k][f0 + 4];
        float xs[4] = {xa.x, xa.y, xa.z, xa.w};
        float wsv[8] = {wa.x, wa.y, wa.z, wa.w, wb.x, wb.y, wb.z, wb.w};
#pragma unroll
        for (int i = 0; i < 4; ++i)
#pragma unroll
            for (int j = 0; j < 8; ++j) acc[i][j] += xs[i] * wsv[j];
    }

#pragma unroll
    for (int i = 0; i < 4; ++i) {
        int nn = nb + n0 + i;
        if (nn < n) {
            float dr = di[nn];                  // fold edge weight into table
            union { __half h[8]; float4 f4; } u;
#pragma unroll
            for (int j = 0; j < 8; ++j) u.h[j] = __float2half(acc[i][j] * dr);
            *(float4*)&C[(size_t)nn * HF + f0] = u.f4;
        }
    }
}

// ---------------- agg: one wave per node, half-wave per edge -----------------
// lanes: half = lane>>5 (edge slot), fh = lane&31 (feature pair 2fh,2fh+1)
// unroll: 8 rows in flight per half-wave (16 edges/wave-iteration)
__device__ __forceinline__ void agg_edges2(const __half2* __restrict__ P2,
                                           const ushort* __restrict__ csrs,
                                           int beg, int deg, int half, int fh,
                                           float& A0, float& A1) {
    float a0 = 0.f, a1 = 0.f, b0 = 0.f, b1 = 0.f;
    int pairs = deg >> 1;           // each pair = 2 edges (one per half)
    int e = beg + half;
    int chunks = pairs >> 3;        // 8 pairs per iteration
    for (int c = 0; c < chunks; ++c, e += 16) {
        int s0 = csrs[e];
        int s1 = csrs[e + 2];
        int s2 = csrs[e + 4];
        int s3 = csrs[e + 6];
        int s4 = csrs[e + 8];
        int s5 = csrs[e + 10];
        int s6 = csrs[e + 12];
        int s7 = csrs[e + 14];
        float2 v0 = __half22float2(P2[(size_t)s0 * 32 + fh]);
        float2 v1 = __half22float2(P2[(size_t)s1 * 32 + fh]);
        float2 v2 = __half22float2(P2[(size_t)s2 * 32 + fh]);
        float2 v3 = __half22float2(P2[(size_t)s3 * 32 + fh]);
        float2 v4 = __half22float2(P2[(size_t)s4 * 32 + fh]);
        float2 v5 = __half22float2(P2[(size_t)s5 * 32 + fh]);
        float2 v6 = __half22float2(P2[(size_t)s6 * 32 + fh]);
        float2 v7 = __half22float2(P2[(size_t)s7 * 32 + fh]);
        a0 += v0.x; a1 += v0.y;
        b0 += v1.x; b1 += v1.y;
        a0 += v2.x; a1 += v2.y;
        b0 += v3.x; b1 += v3.y;
        a0 += v4.x; a1 += v4.y;
        b0 += v5.x; b1 += v5.y;
        a0 += v6.x; a1 += v6.y;
        b0 += v7.x; b1 += v7.y;
    }
    for (int r = pairs & 7; r > 0; --r, e += 2) {
        int s = csrs[e];
        float2 v = __half22float2(P2[(size_t)s * 32 + fh]);
        a0 += v.x; a1 += v.y;
    }
    if ((deg & 1) && half == 0) {
        int s = csrs[beg + deg - 1];
        float2 v = __half22float2(P2[(size_t)s * 32 + fh]);
        a0 += v.x; a1 += v.y;
    }
    a0 += b0; a1 += b1;
    a0 += __shfl_xor(a0, 32);
    a1 += __shfl_xor(a1, 32);
    A0 = a0; A1 = a1;
}

__global__ __launch_bounds__(256) void k_agg(const __half2* __restrict__ P2,
                      const int* __restrict__ offs, const ushort* __restrict__ csrs,
                      const float* __restrict__ di, const float* __restrict__ bias,
                      float* __restrict__ out, int n, float fill) {
    int wid = (blockIdx.x * blockDim.x + threadIdx.x) >> 6;
    if (wid >= n) return;
    int lane = threadIdx.x & 63;
    int half = lane >> 5, fh = lane & 31;
    int beg = offs[wid], deg = offs[wid + 1] - beg;
    float a0, a1;
    agg_edges2(P2, csrs, beg, deg, half, fh, a0, a1);
    float dw = di[wid];
    float2 self = __half22float2(P2[(size_t)wid * 32 + fh]);
    a0 = fmaxf(dw * (a0 + fill * self.x) + bias[2 * fh + 0], 0.f);
    a1 = fmaxf(dw * (a1 + fill * self.y) + bias[2 * fh + 1], 0.f);
    if (half == 0) {
        float* op = &out[(size_t)wid * HF + 2 * fh];
        __builtin_nontemporal_store(a0, op);
        __builtin_nontemporal_store(a1, op + 1);
    }
}

// layer-3 agg fused with output projection: z2 = dp * (relu(agg+b) . Wout)
__global__ __launch_bounds__(256) void k_agg_final(const __half2* __restrict__ P2,
                      const int* __restrict__ offs, const ushort* __restrict__ csrs,
                      const float* __restrict__ di, const float* __restrict__ bias,
                      const float* __restrict__ Wout, const float* __restrict__ dp,
                      float* __restrict__ z2, int n) {
    int wid = (blockIdx.x * blockDim.x + threadIdx.x) >> 6;
    if (wid >= n) return;
    int lane = threadIdx.x & 63;
    int half = lane >> 5, fh = lane & 31;
    int beg = offs[wid], deg = offs[wid + 1] - beg;
    float a0, a1;
    agg_edges2(P2, csrs, beg, deg, half, fh, a0, a1);
    float dw = di[wid];
    float2 self = __half22float2(P2[(size_t)wid * 32 + fh]);
    a0 = fmaxf(dw * (a0 + 2.0f * self.x) + bias[2 * fh + 0], 0.f);
    a1 = fmaxf(dw * (a1 + 2.0f * self.y) + bias[2 * fh + 1], 0.f);
    float v = a0 * Wout[2 * fh] + a1 * Wout[2 * fh + 1];
#pragma unroll
    for (int o = 16; o > 0; o >>= 1) v += __shfl_down(v, o, 32);
    if (lane == 0) z2[wid] = v * dp[wid];
}

// out[n] = dp[n] * (sum_e z2[src] + z2[n]) + b_out   (16 lanes per node)
__global__ __launch_bounds__(256) void k_out(const float* __restrict__ z2,
                      const int* __restrict__ offs, const ushort* __restrict__ csrs,
                      const float* __restrict__ dp, const float* __restrict__ bout,
                      float* __restrict__ out, int n) {
    int node = (blockIdx.x * blockDim.x + threadIdx.x) >> 4;
    if (node >= n) return;
    int l = threadIdx.x & 15;
    int beg = offs[node], end = offs[node + 1];
    float acc = 0.f;
    for (int e = beg + l; e < end; e += 16) acc += z2[csrs[e]];
#pragma unroll
    for (int o = 8; o > 0; o >>= 1) acc += __shfl_down(acc, o, 16);
    if (l == 0) out[node] = dp[node] * (acc + z2[node]) + bout[0];
}

extern "C" void kernel_launch(void* const* d_in, const int* in_sizes, int n_in,
                              void* d_out, int out_size, void* d_ws, size_t ws_size,
                              hipStream_t stream) {
    const float* x    = (const float*)d_in[0];
    const int*   ei   = (const int*)d_in[1];
    const float* W_in = (const float*)d_in[2];
    const float* b_in = (const float*)d_in[3];
    const float* W_h1 = (const float*)d_in[4];
    const float* b_h1 = (const float*)d_in[5];
    const float* W_h2 = (const float*)d_in[6];
    const float* b_h2 = (const float*)d_in[7];
    const float* W_out= (const float*)d_in[8];
    const float* b_out= (const float*)d_in[9];
    float* out = (float*)d_out;

    const int n = in_sizes[0] / HF;        // 50000 (< 65536: ushort CSR ok)
    const int E = in_sizes[1] / 2;         // 1.6M
    const int* src = ei;
    const int* dst = ei + E;

    const int G  = (E + EPB - 1) / EPB;    // 98
    const int NB = (n + 255) >> 8;

    char* ws = (char*)d_ws;
    size_t o = 0;
    auto alloc = [&](size_t bytes) -> void* {
        void* p = ws + o;
        o += (bytes + 255) & ~(size_t)255;
        return p;
    };
    int*          offs   = (int*)   alloc((size_t)(n + 1) * 4);
    float*        di     = (float*) alloc((size_t)n * 4);
    float*        dp     = (float*) alloc((size_t)n * 4);
    ushort*       csrs   = (ushort*)alloc((size_t)E * 2);
    unsigned int* tmp    = (unsigned int*)alloc((size_t)E * 4);
    int*          histT  = (int*)   alloc((size_t)G * 256 * 4);
    int*          bsum   = (int*)   alloc(256 * 4);
    int*          coarse = (int*)   alloc(257 * 4);
    __half*       hW     = (__half*)alloc((size_t)n * HF * 2);   // fp16 P' table
    float*        hA     = (float*) alloc((size_t)n * HF * 4);
    float*        hB     = (float*) alloc((size_t)n * HF * 4);
    float*        z2     = (float*) alloc((size_t)n * 4);

    const int TB = 256;
    int gbW  = (n * 64 + TB - 1) / TB;
    int gbO  = (n * 16 + TB - 1) / TB;
    int gbG  = (n + GM_BN - 1) / GM_BN;

    // ---- CSR build (atomic-free, LDS atomics only; two-level scan) ----
    pA_hist   <<<G,   TB, 0, stream>>>(dst, histT, E, G);
    pScan1    <<<256, 128, 0, stream>>>(histT, bsum, G);
    pScan2    <<<1,   TB, 0, stream>>>(bsum, coarse, E);
    pB_scatter<<<G,   TB, 0, stream>>>(src, dst, histT, coarse, tmp, E, G);
    pC_build  <<<NB,  TB, 0, stream>>>(tmp, coarse, csrs, offs, di, dp, n, E, NB);

    const __half2* hW2 = (const __half2*)hW;

    // ---- layer 1 ----
    k_gemm<<<gbG, TB, 0, stream>>>(x, W_in, di, hW, n);
    k_agg<<<gbW, TB, 0, stream>>>(hW2, offs, csrs, di, b_in, hA, n, 2.0f);
    // ---- layer 2 ----
    k_gemm<<<gbG, TB, 0, stream>>>(hA, W_h1, di, hW, n);
    k_agg<<<gbW, TB, 0, stream>>>(hW2, offs, csrs, di, b_h1, hB, n, 2.0f);
    // ---- layer 3 (agg fused with output projection) ----
    k_gemm<<<gbG, TB, 0, stream>>>(hB, W_h2, di, hW, n);
    k_agg_final<<<gbW, TB, 0, stream>>>(hW2, offs, csrs, di, b_h2, W_out, dp, z2, n);
    // ---- output layer ----
    k_out<<<gbO, TB, 0, stream>>>(z2, offs, csrs, dp, b_out, out, n);
}